// Round 4
// baseline (178.038 us; speedup 1.0000x reference)
//
#include <hip/hip_runtime.h>
#include <hip/hip_bf16.h>

typedef short s16x8 __attribute__((ext_vector_type(8)));
typedef float f32x4 __attribute__((ext_vector_type(4)));
typedef float f32x2 __attribute__((ext_vector_type(2)));
typedef unsigned int u32x4 __attribute__((ext_vector_type(4)));

constexpr int Bb = 2, NQ = 13294, Hh = 8, HD = 32;
constexpr int Mrows = Bb * NQ; // 26588

__device__ inline short bf16_of(float f) {
  __hip_bfloat16 h = __float2bfloat16(f);
  return *reinterpret_cast<short*>(&h);
}

// C = A[M,256] @ W[256,N] + bias. A: fp32 or bf16 (ABF16). W,bias fp32.
// f32 accum via bf16 MFMA. 64x64 tile, 4 waves. Grid: (colTiles, rowTiles)
// -> col fastest so one A row-panel's col-tiles co-run (A fetched ~once).
// MODE 0: bf16 scatter to vproj[B][H][NQ][HD]
// MODE 1: FUSED query GEMM: colTile<4 -> Wso (N=256) to offaw[row*384+col];
//         colTile>=4 -> Waw (N=128) to offaw[row*384+256+col]
// MODE 3: fp32 linear stride 256 (d_out)
template<int MODE, bool ABF16>
__global__ __launch_bounds__(256) void gemm_k(
    const void* __restrict__ Araw, const float* __restrict__ W,
    const float* __restrict__ bias, void* __restrict__ outraw,
    const float* __restrict__ W2, const float* __restrict__ bias2)
{
  __shared__ short As[64][40];   // +8 pad: breaks bank conflict on ds_read_b128
  __shared__ short Bs[64][40];   // Bs[n][k] (B staged transposed)
  const int row0 = blockIdx.y * 64;
  const int tid = threadIdx.x;
  const int lane = tid & 63, wave = tid >> 6;

  const float* Wp = W; const float* bp = bias;
  int Nw = 256, colb = blockIdx.x * 64, outoff = 0;
  if constexpr (MODE == 1) {
    if (blockIdx.x >= 4) { Wp = W2; bp = bias2; Nw = 128; colb = (blockIdx.x - 4) * 64; outoff = 256; }
  }

  f32x4 acc[4] = {};
  const int ar = tid >> 2, ak = (tid & 3) * 8;       // A stage: 64 rows x 32 k
  int grow = row0 + ar; if (grow >= Mrows) grow = Mrows - 1;
  const int kk = tid & 31, nb = (tid >> 5) * 8;      // B stage: transpose on write

  for (int kt = 0; kt < 256; kt += 32) {
    s16x8 av;
    if constexpr (ABF16) {
      av = *(const s16x8*)((const short*)Araw + grow * 256 + kt + ak);
    } else {
      const float* A = (const float*)Araw;
      f32x4 a0 = *(const f32x4*)(A + grow * 256 + kt + ak);
      f32x4 a1 = *(const f32x4*)(A + grow * 256 + kt + ak + 4);
#pragma unroll
      for (int i = 0; i < 4; i++) { av[i] = bf16_of(a0[i]); av[4 + i] = bf16_of(a1[i]); }
    }
    *(s16x8*)(&As[ar][ak]) = av;

    f32x4 w0 = *(const f32x4*)(Wp + (kt + kk) * Nw + colb + nb);
    f32x4 w1 = *(const f32x4*)(Wp + (kt + kk) * Nw + colb + nb + 4);
#pragma unroll
    for (int i = 0; i < 4; i++) { Bs[nb + i][kk] = bf16_of(w0[i]); Bs[nb + 4 + i][kk] = bf16_of(w1[i]); }
    __syncthreads();

    s16x8 bfr = *(const s16x8*)(&Bs[wave * 16 + (lane & 15)][(lane >> 4) * 8]);
#pragma unroll
    for (int m = 0; m < 4; m++) {
      s16x8 afr = *(const s16x8*)(&As[m * 16 + (lane & 15)][(lane >> 4) * 8]);
      acc[m] = __builtin_amdgcn_mfma_f32_16x16x32_bf16(afr, bfr, acc[m], 0, 0, 0);
    }
    __syncthreads();
  }

  // D mapping: col = lane&15, row = (lane>>4)*4 + reg
  const int colL = colb + wave * 16 + (lane & 15);
  const float bvf = bp[colL];
#pragma unroll
  for (int m = 0; m < 4; m++) {
#pragma unroll
    for (int r = 0; r < 4; r++) {
      int rowL = row0 + m * 16 + (lane >> 4) * 4 + r;
      if (rowL < Mrows) {
        float v = acc[m][r] + bvf;
        if constexpr (MODE == 0) {
          int b = rowL / NQ, n = rowL - (rowL / NQ) * NQ;
          int h = colL >> 5, c = colL & 31;
          ((__hip_bfloat16*)outraw)[((b * Hh + h) * NQ + n) * HD + c] = __float2bfloat16(v);
        } else if constexpr (MODE == 1) {
          ((__hip_bfloat16*)outraw)[rowL * 384 + outoff + colL] = __float2bfloat16(v);
        } else {
          ((float*)outraw)[rowL * 256 + colL] = v;
        }
      }
    }
  }
}

// 2 queries per block, 256 threads = 4 waves.
// Phase A: each thread = one (q,h,l,p): descriptor + fused 16-wide softmax.
// Phase B: wave handles 4 (q,h) pairs; per pair 4 steps; per step the wave
// reads 16 rows as dwordx4 (4 lanes/row, 8 ch/lane), pk-FMA into float2 acc,
// then 4-round shfl_xor reduce over the 16 row-slots.
__global__ __launch_bounds__(256) void sample_k(
    const __hip_bfloat16* __restrict__ vproj,
    const __hip_bfloat16* __restrict__ offaw,
    const float* __restrict__ refp,
    __hip_bfloat16* __restrict__ interm)
{
  __shared__ float dw[2][8][16][4];
  __shared__ int   didx[2][8][16][4];
  const int tid = threadIdx.x;
  const int bq0 = blockIdx.x * 2;

  { // Phase A
    const int q = tid >> 7, h = (tid >> 4) & 7, lp = tid & 15;
    const int l = lp >> 2;
    const int bq = bq0 + q;
    const int b = bq / NQ;
    const int dims[4]   = {100, 50, 25, 13};
    const int starts[4] = {0, 10000, 12500, 13125};
    const int lw = dims[l], lh = lw;
    const int base384 = bq * 384;
    unsigned int oxy = *(const unsigned int*)((const unsigned short*)offaw + base384 + h * 32 + lp * 2);
    float offx = __uint_as_float(oxy << 16);
    float offy = __uint_as_float(oxy & 0xffff0000u);
    float logit = __bfloat162float(offaw[base384 + 256 + h * 16 + lp]);
    float rx = refp[(bq * 4 + l) * 2 + 0];
    float ry = refp[(bq * 4 + l) * 2 + 1];
    // align_corners=False: gx = loc_x*lw - 0.5 = rx*lw + offx - 0.5
    float gx = rx * (float)lw + offx - 0.5f;
    float gy = ry * (float)lh + offy - 0.5f;
    float mx = logit;
#pragma unroll
    for (int d = 1; d < 16; d <<= 1) mx = fmaxf(mx, __shfl_xor(mx, d));
    float e = __expf(logit - mx);
    float s = e;
#pragma unroll
    for (int d = 1; d < 16; d <<= 1) s += __shfl_xor(s, d);
    float aw = e / s;
    float x0f = floorf(gx), y0f = floorf(gy);
    int x0 = (int)x0f, y0 = (int)y0f;
    float wx = gx - x0f, wy = gy - y0f;
    const int pbase = (b * Hh + h) * NQ + starts[l];
#pragma unroll
    for (int k = 0; k < 4; k++) {
      int xi = x0 + (k & 1), yi = y0 + (k >> 1);
      bool valid = (xi >= 0) && (xi < lw) && (yi >= 0) && (yi < lh);
      int xc = min(max(xi, 0), lw - 1), yc = min(max(yi, 0), lh - 1);
      float wcv = ((k & 1) ? wx : 1.f - wx) * ((k >> 1) ? wy : 1.f - wy);
      dw[q][h][lp][k]   = valid ? wcv * aw : 0.f;
      didx[q][h][lp][k] = pbase + yc * lw + xc;
    }
  }
  __syncthreads();

  const int wv = tid >> 6, lane = tid & 63;
  const int voff = (lane & 3) * 16;          // 16B channel slice within row
  const int slot = lane >> 4;                // sample sub-slot
  const int cor  = (lane >> 2) & 3;          // corner
#pragma unroll
  for (int i = 0; i < 4; i++) {
    const int pair = wv * 4 + i;
    const int q = pair >> 3, h = pair & 7;
    f32x2 acc2[4] = {};
#pragma unroll
    for (int t = 0; t < 4; t++) {
      const int s = t * 4 + slot;
      const int idx = didx[q][h][s][cor];
      const float w = dw[q][h][s][cor];
      const u32x4 u = *(const u32x4*)((const char*)vproj + ((size_t)idx << 6) + voff);
      const f32x2 wb = {w, w};
#pragma unroll
      for (int j = 0; j < 4; j++) {
        f32x2 v2 = { __uint_as_float(u[j] << 16), __uint_as_float(u[j] & 0xffff0000u) };
        acc2[j] += v2 * wb;   // v_pk_fma_f32-able
      }
    }
    // reduce over 16 row-slots (lanes sharing lane&3)
#pragma unroll
    for (int m = 4; m <= 32; m <<= 1) {
#pragma unroll
      for (int j = 0; j < 4; j++) {
        acc2[j][0] += __shfl_xor(acc2[j][0], m);
        acc2[j][1] += __shfl_xor(acc2[j][1], m);
      }
    }
    if (lane < 4) {
      unsigned int up[4];
#pragma unroll
      for (int j = 0; j < 4; j++) {
        unsigned int b0 = (unsigned int)(unsigned short)bf16_of(acc2[j][0]);
        unsigned int b1 = (unsigned int)(unsigned short)bf16_of(acc2[j][1]);
        up[j] = (b1 << 16) | b0;
      }
      u32x4 pk = { up[0], up[1], up[2], up[3] };
      *(u32x4*)((unsigned short*)interm + (size_t)(bq0 + q) * 256 + h * 32 + lane * 8) = pk;
    }
  }
}

extern "C" void kernel_launch(void* const* d_in, const int* in_sizes, int n_in,
                              void* d_out, int out_size, void* d_ws, size_t ws_size,
                              hipStream_t stream)
{
  const float* query = (const float*)d_in[0];
  const float* refp  = (const float*)d_in[1];
  const float* value = (const float*)d_in[2];
  // d_in[3] = spatial_shapes (static, hardcoded)
  const float* Wso = (const float*)d_in[4];
  const float* bso = (const float*)d_in[5];
  const float* Waw = (const float*)d_in[6];
  const float* baw = (const float*)d_in[7];
  const float* Wv  = (const float*)d_in[8];
  const float* bv  = (const float*)d_in[9];
  const float* Wo  = (const float*)d_in[10];
  const float* bo  = (const float*)d_in[11];

  char* ws = (char*)d_ws;
  __hip_bfloat16* vproj  = (__hip_bfloat16*)ws;                 // 13,613,056 B
  __hip_bfloat16* offaw  = (__hip_bfloat16*)(ws + 13613056);    // 20,419,584 B
  __hip_bfloat16* interm = (__hip_bfloat16*)(ws + 34032640);    // 13,613,056 B
  float* out = (float*)d_out;

  dim3 blk(256);
  gemm_k<0, false><<<dim3(4, 416), blk, 0, stream>>>(value, Wv, bv, vproj, nullptr, nullptr);
  gemm_k<1, false><<<dim3(6, 416), blk, 0, stream>>>(query, Wso, bso, offaw, Waw, baw);
  sample_k<<<dim3(Mrows / 2), blk, 0, stream>>>(vproj, offaw, refp, interm);
  gemm_k<3, true><<<dim3(4, 416), blk, 0, stream>>>(interm, Wo, bo, out, nullptr, nullptr);
}